// Round 17
// baseline (1661.577 us; speedup 1.0000x reference)
//
#include <hip/hip_runtime.h>
#include <hip/hip_fp8.h>
#include <math.h>
#include <stdint.h>

#define B_ROWS 4096
#define D_DIM  768
#define M_ROWS 100000
#define K_TOP  10

// ---------------- MFMA-path constants ----------------
#define KSTEPS 48          // 768 / 16
#define E32N   3125        // evidence 32-row tiles
#define B32N   128         // batch 32-row tiles
#define NGRP   48          // evidence groups (grid = 16 bb x 48 g = 768 blocks)
#define NBB    16
#define NIT4   782         // ceil(3125/4): block-iterations of 128 evid rows
#define CAND   6           // candidates kept per (row, group)  (48*6 = 288/row)
#define KCN    12          // K-chunks of 64 per j
#define LTK    5           // per-lane top-k length (4 lists/column)
#define TILEB  24576       // bytes per 32-row fp8 fragment tile (48 ks * 512)

typedef long i64;
typedef float f32x16 __attribute__((ext_vector_type(16)));

// workspace layout (bytes)
#define XF_BYTES (128ull * TILEB)
#define EF_OFF   XF_BYTES
#define EF_BYTES (3125ull * TILEB)
#define CS_OFF   (EF_OFF + EF_BYTES)
#define CS_BYTES (4096ull * NGRP * CAND * 4)
#define CI_OFF   (CS_OFF + CS_BYTES)
#define CI_BYTES (4096ull * NGRP * CAND * 4)
#define WS_NEED  (CI_OFF + CI_BYTES)

// ---------------------------------------------------------------------------
// Convert fp32 [rows][768] -> fp8 e4m3 fragment-tiled
// [band32][ks48][lane64][j8] bytes.
// ---------------------------------------------------------------------------
__global__ __launch_bounds__(256) void convert_frag8(
    const float* __restrict__ src, uint8_t* __restrict__ dst, int nband)
{
  int tid  = blockIdx.x * 256 + threadIdx.x;
  int l    = tid & 63;
  int rest = tid >> 6;
  int ks   = rest % KSTEPS;
  int band = rest / KSTEPS;
  if (band >= nband) return;
  int row = band * 32 + (l & 31);
  int k0  = ks * 16 + 8 * (l >> 5);
  const float* s = src + (size_t)row * D_DIM + k0;
  float4 v0 = *(const float4*)s;
  float4 v1 = *(const float4*)(s + 4);
  unsigned long long o = 0;
  o |= (unsigned long long)(__hip_fp8_e4m3(v0.x).__x) << 0;
  o |= (unsigned long long)(__hip_fp8_e4m3(v0.y).__x) << 8;
  o |= (unsigned long long)(__hip_fp8_e4m3(v0.z).__x) << 16;
  o |= (unsigned long long)(__hip_fp8_e4m3(v0.w).__x) << 24;
  o |= (unsigned long long)(__hip_fp8_e4m3(v1.x).__x) << 32;
  o |= (unsigned long long)(__hip_fp8_e4m3(v1.y).__x) << 40;
  o |= (unsigned long long)(__hip_fp8_e4m3(v1.z).__x) << 48;
  o |= (unsigned long long)(__hip_fp8_e4m3(v1.w).__x) << 56;
  *(unsigned long long*)(dst + ((size_t)(band * KSTEPS + ks) << 9) + l * 8) = o;
}

// sorted top-5 insert (descending), static-indexed
__device__ __forceinline__ void ins5(float (&ts)[LTK], int (&ti)[LTK],
                                     float s, int idx)
{
  ts[LTK - 1] = s; ti[LTK - 1] = idx;
#pragma unroll
  for (int q = LTK - 1; q > 0; --q) {
    if (ts[q] > ts[q - 1]) {
      float a = ts[q]; ts[q] = ts[q - 1]; ts[q - 1] = a;
      int   b = ti[q]; ti[q] = ti[q - 1]; ti[q - 1] = b;
    }
  }
}

__device__ __forceinline__ float max16(const f32x16& v)
{
  float a = fmaxf(fmaxf(v[0], v[1]), fmaxf(v[2], v[3]));
  float b = fmaxf(fmaxf(v[4], v[5]), fmaxf(v[6], v[7]));
  float c = fmaxf(fmaxf(v[8], v[9]), fmaxf(v[10], v[11]));
  float d = fmaxf(fmaxf(v[12], v[13]), fmaxf(v[14], v[15]));
  return fmaxf(fmaxf(a, b), fmaxf(c, d));
}

__device__ __forceinline__ void gll16(const void* src, void* dst)
{
  __builtin_amdgcn_global_load_lds(
      (const __attribute__((address_space(1))) void*)(uintptr_t)src,
      (__attribute__((address_space(3))) void*)(uint32_t)(uintptr_t)dst,
      16, 0, 0);
}

// ---------------------------------------------------------------------------
// GEMM + fused per-lane top-k, fp8 e4m3.  r13's proven schedule, block shrunk
// to 8 waves / 48 KB LDS so THREE independent blocks co-reside per CU
// (3 x 48 KB = 144 <= 160 KB; 24 waves/CU): when one block sits in its
// vmcnt(0)+barrier drain, the other two blocks' waves compute.
// Per block-iteration j: 128 evid x 256 batch, K=768.
// 8 waves = 2 evid-waves x 4 batch-waves, 2x2 tiles each.
// Buffer (24576 B): E tiles 0..3 at et*2048; X tiles 0..7 at 8192+xt*2048;
// frag kk at +kk*512.  Waves 0..3 stage E tile w (2 glls); waves 4..7 stage
// X tiles 2(w-4),2(w-4)+1 (4 glls).
// Merge scratch: ds = 20 KB at lds+0, di = 20 KB at lds+24576 (disjoint).
// ---------------------------------------------------------------------------
__global__ __launch_bounds__(512, 6) void gemm_topk(
    const uint8_t* __restrict__ Ef, const uint8_t* __restrict__ Xf,
    float* __restrict__ cs, int* __restrict__ ci)
{
  __shared__ char lds[2][24576];   // 2 x 24 KB (double buffer)

  const int t    = threadIdx.x;
  const int lane = t & 63;
  const int w    = t >> 6;      // 0..7
  const int ew   = w >> 2;      // 0..1  evid-wave (2 e-tiles each)
  const int bw   = w & 3;       // 0..3  batch-wave (2 x-tiles each)

  // XCD-aware remap: id%8 = XCD; each XCD hosts 6 g-values x all 16 bb.
  const int id  = blockIdx.x;           // 0..767
  const int xcd = id & 7;
  const int q8  = id >> 3;              // 0..95
  const int bb  = q8 & 15;              // batch block 0..15
  const int g   = xcd * 6 + (q8 >> 4);  // evidence group 0..47
  const int niter = 16 + (g < (NIT4 - NGRP * 16) ? 1 : 0);   // 782 = 48*16+14

  const bool isE = (w < 4);
  const uint32_t dE  = (uint32_t)w * 2048 + lane * 16;            // E tile w
  const uint32_t dX0 = 8192u + (uint32_t)(2 * (w - 4)) * 2048 + lane * 16;
  const uint32_t dX1 = dX0 + 2048;

  // X staging sources (j-invariant)
  const uint8_t* xb0 = Xf + (size_t)(bb * 8 + 2 * (w - 4)) * TILEB + lane * 16;
  const uint8_t* xb1 = xb0 + TILEB;

  auto STAGE = [&](const uint8_t* s0, const uint8_t* s1, char* base) {
    if (isE) {
      gll16(s0,        base + dE);
      gll16(s0 + 1024, base + dE + 1024);
    } else {
      gll16(s0,        base + dX0);
      gll16(s0 + 1024, base + dX0 + 1024);
      gll16(s1,        base + dX1);
      gll16(s1 + 1024, base + dX1 + 1024);
    }
  };

  float ts0[LTK], ts1[LTK]; int ti0[LTK], ti1[LTK];
#pragma unroll
  for (int q = 0; q < LTK; ++q) {
    ts0[q] = -INFINITY; ts1[q] = -INFINITY;
    ti0[q] = 0x7fffffff; ti1[q] = 0x7fffffff;
  }

  char* buf0 = &lds[0][0];
  char* buf1 = &lds[1][0];
  const char* rb0p = buf0 + lane * 8;
  const char* rb1p = buf1 + lane * 8;

#pragma unroll 1
  for (int j = 0; j < niter; ++j) {
    const int it = g + NGRP * j;          // global 128-row block-iteration

    const uint8_t* sE = xb0;              // placeholder for X waves
    if (isE) {
      int e32 = it * 4 + w; if (e32 > E32N - 1) e32 = E32N - 1;
      sE = Ef + (size_t)e32 * TILEB + lane * 16;
    }

    f32x16 acc0[2], acc1[2];
#pragma unroll
    for (int e = 0; e < 2; ++e) {
#pragma unroll
      for (int q = 0; q < 16; ++q) { acc0[e][q] = 0.f; acc1[e][q] = 0.f; }
    }

    // stage chunk 0 into buf0 (freed by previous j's final barrier)
    const uint8_t* sc0 = isE ? sE : xb0;
    const uint8_t* sc1 = xb1;
    STAGE(sc0, sc1, buf0);
    sc0 += 2048; sc1 += 2048;

#pragma unroll 1
    for (int kc = 0; kc < KCN; ++kc) {
      asm volatile("s_waitcnt vmcnt(0)" ::: "memory"); // chunk-kc loads landed
      __builtin_amdgcn_s_barrier();                    // this block staged kc

      const char* rp = (kc & 1) ? rb1p : rb0p;
      char* dp = (kc & 1) ? buf0 : buf1;

      if (kc < KCN - 1) {                              // stage chunk kc+1 early
        STAGE(sc0, sc1, dp);
        sc0 += 2048; sc1 += 2048;
      }

#pragma unroll
      for (int kk = 0; kk < 4; ++kk) {
        i64 a[2], b[2];
#pragma unroll
        for (int e = 0; e < 2; ++e)
          a[e] = *(const i64*)(rp + ((ew * 2 + e) * 2048 + kk * 512));
#pragma unroll
        for (int x2 = 0; x2 < 2; ++x2)
          b[x2] = *(const i64*)(rp + (8192 + (bw * 2 + x2) * 2048 + kk * 512));
#pragma unroll
        for (int e = 0; e < 2; ++e) {
          acc0[e] = __builtin_amdgcn_mfma_f32_32x32x16_fp8_fp8(a[e], b[0], acc0[e], 0, 0, 0);
          acc1[e] = __builtin_amdgcn_mfma_f32_32x32x16_fp8_fp8(a[e], b[1], acc1[e], 0, 0, 0);
        }
      }
    }

    // inserts, max-prefiltered per 16-value tile
    // C/D map: col=lane&31, row=(q&3)+8*(q>>2)+4*(lane>>5)
#pragma unroll
    for (int e = 0; e < 2; ++e) {
      const int ebase = (it * 4 + ew * 2 + e) * 32 + 4 * (lane >> 5);
      if (max16(acc0[e]) > ts0[LTK - 1]) {
#pragma unroll
        for (int q = 0; q < 16; ++q) {
          int eidx = ebase + (q & 3) + 8 * (q >> 2);
          float s = acc0[e][q];
          if (eidx < M_ROWS && s > ts0[LTK - 1]) ins5(ts0, ti0, s, eidx);
        }
      }
      if (max16(acc1[e]) > ts1[LTK - 1]) {
#pragma unroll
        for (int q = 0; q < 16; ++q) {
          int eidx = ebase + (q & 3) + 8 * (q >> 2);
          float s = acc1[e][q];
          if (eidx < M_ROWS && s > ts1[LTK - 1]) ins5(ts1, ti1, s, eidx);
        }
      }
    }
  }

  // ---- merge per batch-col: 4 lists (2 evid-waves x 2 lane-halves) -> top-6
  // ds = 5120 floats (20 KB) at lds+0; di = 5120 ints (20 KB) at lds+24576.
  __syncthreads();
  float* ds = (float*)&lds[0][0];
  int*   di = (int*)(&lds[0][0] + 24576);
  {
    int half = lane >> 5, cl = lane & 31;
    int base0 = ((((ew * 2 + half) * 4 + bw) * 2 + 0) * 32 + cl) * LTK;
    int base1 = ((((ew * 2 + half) * 4 + bw) * 2 + 1) * 32 + cl) * LTK;
#pragma unroll
    for (int q = 0; q < LTK; ++q) {
      ds[base0 + q] = ts0[q]; di[base0 + q] = ti0[q];
      ds[base1 + q] = ts1[q]; di[base1 + q] = ti1[q];
    }
  }
  __syncthreads();
  if (t < 256) {
    int c = t; int bw2 = c >> 6, bt2 = (c >> 5) & 1, cl2 = c & 31;
    int hb[4];
#pragma unroll
    for (int u = 0; u < 4; ++u) {
      int ew2 = u >> 1, h2 = u & 1;
      hb[u] = ((((ew2 * 2 + h2) * 4 + bw2) * 2 + bt2) * 32 + cl2) * LTK;
    }
    const int row = bb * 256 + c;
    float* ocs = cs + ((size_t)row * NGRP + g) * CAND;
    int*   oci = ci + ((size_t)row * NGRP + g) * CAND;
    for (int o = 0; o < CAND; ++o) {
      float best = -INFINITY; int bidx = 0x7fffffff; int bu = 0, bq = 0;
#pragma unroll
      for (int u = 0; u < 4; ++u) {
        for (int q = 0; q < LTK; ++q) {
          float s = ds[hb[u] + q]; int id2 = di[hb[u] + q];
          if (s > best || (s == best && id2 < bidx)) { best = s; bidx = id2; bu = u; bq = q; }
        }
      }
      ds[hb[bu] + bq] = -INFINITY;
      ocs[o] = best; oci[o] = bidx;
    }
  }
}

// ---------------------------------------------------------------------------
// Final: per row merge 48*6=288 candidates -> approx top-32 (fp8 noise
// margin — the r13/r15-proven width; r16's top-16 was too narrow and failed)
// -> fp64 rescore -> exact-ordered top-10.
// ---------------------------------------------------------------------------
#define NCAND (NGRP * CAND)   // 288

__global__ __launch_bounds__(64) void final_merge(
    const float* __restrict__ x, const float* __restrict__ E,
    const float* __restrict__ cs, const int* __restrict__ ci,
    float* __restrict__ out)
{
  __shared__ float ls[NCAND]; __shared__ int li[NCAND];
  __shared__ int c32[32]; __shared__ double rs[32];
  const int row = blockIdx.x;
  const int lane = threadIdx.x;
  for (int q = lane; q < NCAND; q += 64) {
    ls[q] = cs[(size_t)row * NCAND + q];
    li[q] = ci[(size_t)row * NCAND + q];
  }
  __syncthreads();

  for (int o = 0; o < 32; ++o) {
    float bs = -INFINITY; int bi = 0x7fffffff; int bp = 0;
    for (int q = lane; q < NCAND; q += 64) {
      float s = ls[q];
      if (s > bs || (s == bs && li[q] < bi)) { bs = s; bi = li[q]; bp = q; }
    }
#pragma unroll
    for (int mk = 1; mk <= 32; mk <<= 1) {
      float qs = __shfl_xor(bs, mk, 64);
      int   qi = __shfl_xor(bi, mk, 64);
      int   qp = __shfl_xor(bp, mk, 64);
      if (qs > bs || (qs == bs && qi < bi)) { bs = qs; bi = qi; bp = qp; }
    }
    if (lane == 0) { c32[o] = bi; ls[bp] = -INFINITY; }
    __syncthreads();
  }

  {
    int cd = lane >> 1, p = lane & 1;      // 2 lanes per candidate, 384 elems
    int cid = c32[cd];
    if ((unsigned)cid >= M_ROWS) cid = 0;  // defensive: wrong, not a fault
    const float* Er = E + (size_t)cid * D_DIM + p * 384;
    const float* Xr = x + (size_t)row * D_DIM + p * 384;
    double s = 0.0;
#pragma unroll 8
    for (int d = 0; d < 384; ++d) s += (double)Xr[d] * (double)Er[d];
    s += __shfl_xor(s, 1, 64);
    if (p == 0) rs[cd] = s;
  }
  __syncthreads();

  if (lane == 0) {
    for (int o = 0; o < K_TOP; ++o) {
      double bs = rs[0]; int bc = c32[0]; int b = 0;
      for (int q = 1; q < 32; ++q) {
        double v = rs[q]; int cq = c32[q];
        if (v > bs || (v == bs && cq < bc)) { bs = v; bc = cq; b = q; }
      }
      out[(size_t)row * K_TOP + o] = (float)bs;
      out[(size_t)B_ROWS * K_TOP + (size_t)row * K_TOP + o] = (float)bc;
      rs[b] = -1.0e300;
    }
  }
}

// ---------------------------------------------------------------------------
// Fallback (round-2 kernel) if ws_size is insufficient.
// ---------------------------------------------------------------------------
#define RB   16
#define GQ   64
#define MMF  4
#define NJ   391
#define NTF  1024
#define XPAD 772
#define DQ4  192

__global__ __launch_bounds__(NTF, 4) void retr_fused(
    const float* __restrict__ x, const float* __restrict__ E,
    float* __restrict__ out)
{
  __shared__ float smem[21248];
  const int t = threadIdx.x;
  const int r = t & 15;
  const int g = t >> 4;
  const int rb0 = blockIdx.x * RB;
  {
    const float4* xg = (const float4*)(x + (size_t)rb0 * D_DIM);
    for (int q = t; q < RB * DQ4; q += NTF) {
      int row = q / DQ4, c4 = q % DQ4;
      float4 v = xg[q];
      *(float4*)(smem + row * XPAD + c4 * 4) = v;
    }
  }
  __syncthreads();
  float ts[K_TOP]; int ti[K_TOP];
#pragma unroll
  for (int q = 0; q < K_TOP; ++q) { ts[q] = -INFINITY; ti[q] = 0x7fffffff; }
  const float4* xr4 = (const float4*)(smem + r * XPAD);
  for (int j = 0; j < NJ; ++j) {
    const int m0 = (g + (j << 6)) * MMF;
    const float4* ep[MMF];
#pragma unroll
    for (int mm = 0; mm < MMF; ++mm) {
      int ml = m0 + mm;
      int mc = (ml < M_ROWS) ? ml : (M_ROWS - 1);
      ep[mm] = (const float4*)(E + (size_t)mc * D_DIM);
    }
    float4 acc[MMF];
#pragma unroll
    for (int mm = 0; mm < MMF; ++mm) acc[mm] = make_float4(0.f, 0.f, 0.f, 0.f);
#pragma unroll 4
    for (int dq = 0; dq < DQ4; ++dq) {
      float4 xv = xr4[dq];
#pragma unroll
      for (int mm = 0; mm < MMF; ++mm) {
        float4 e = ep[mm][dq];
        acc[mm].x += e.x * xv.x; acc[mm].y += e.y * xv.y;
        acc[mm].z += e.z * xv.z; acc[mm].w += e.w * xv.w;
      }
    }
#pragma unroll
    for (int mm = 0; mm < MMF; ++mm) {
      int ml = m0 + mm;
      float s = (acc[mm].x + acc[mm].y) + (acc[mm].z + acc[mm].w);
      if (ml < M_ROWS && s > ts[K_TOP - 1]) {
        ts[K_TOP - 1] = s; ti[K_TOP - 1] = ml;
#pragma unroll
        for (int q = K_TOP - 1; q > 0; --q) {
          if (ts[q] > ts[q - 1]) {
            float tf = ts[q]; ts[q] = ts[q - 1]; ts[q - 1] = tf;
            int   tq = ti[q]; ti[q] = ti[q - 1]; ti[q - 1] = tq;
          }
        }
      }
    }
  }
  __syncthreads();
  float*  cs  = smem;
  int*    ci  = (int*)(smem + 10240);
  int*    cnd = (int*)(smem + 20480);
  double* rsd = (double*)(smem + 20736);
#pragma unroll
  for (int q = 0; q < K_TOP; ++q) {
    cs[(r * GQ + g) * K_TOP + q] = ts[q];
    ci[(r * GQ + g) * K_TOP + q] = ti[q];
  }
  __syncthreads();
  const int w = t >> 6;
  const int lane = t & 63;
  {
    float ms[K_TOP]; int mi[K_TOP];
#pragma unroll
    for (int q = 0; q < K_TOP; ++q) {
      ms[q] = cs[(w * GQ + lane) * K_TOP + q];
      mi[q] = ci[(w * GQ + lane) * K_TOP + q];
    }
    for (int o = 0; o < 16; ++o) {
      float hs = ms[0]; int hi = mi[0];
      float bs = hs;    int bi = hi;
#pragma unroll
      for (int mk = 1; mk <= 32; mk <<= 1) {
        float qs = __shfl_xor(bs, mk, 64);
        int   qi = __shfl_xor(bi, mk, 64);
        if (qs > bs || (qs == bs && qi < bi)) { bs = qs; bi = qi; }
      }
      bool win = (hs == bs) && (hi == bi);
      if (win) {
#pragma unroll
        for (int q = 0; q < K_TOP - 1; ++q) { ms[q] = ms[q + 1]; mi[q] = mi[q + 1]; }
        ms[K_TOP - 1] = -INFINITY; mi[K_TOP - 1] = 0x7fffffff;
      }
      if (lane == 0) cnd[w * 16 + o] = bi;
    }
  }
  __syncthreads();
  {
    int cand = lane >> 2, p = lane & 3;
    int cid = cnd[w * 16 + cand];
    const float* Er = E + (size_t)cid * D_DIM + p * 192;
    const float* Xr = x + (size_t)(rb0 + w) * D_DIM + p * 192;
    double s = 0.0;
#pragma unroll 8
    for (int d = 0; d < 192; ++d) s += (double)Xr[d] * (double)Er[d];
    s += __shfl_xor(s, 1, 64);
    s += __shfl_xor(s, 2, 64);
    if (p == 0) rsd[w * 16 + cand] = s;
  }
  __syncthreads();
  if (lane == 0) {
    const int row = rb0 + w;
    for (int o = 0; o < K_TOP; ++o) {
      double bsv = rsd[w * 16 + 0]; int bci = cnd[w * 16 + 0]; int b = 0;
      for (int q = 1; q < 16; ++q) {
        double v = rsd[w * 16 + q]; int c = cnd[w * 16 + q];
        if (v > bsv || (v == bsv && c < bci)) { bsv = v; bci = c; b = q; }
      }
      out[(size_t)row * K_TOP + o] = (float)bsv;
      out[(size_t)B_ROWS * K_TOP + (size_t)row * K_TOP + o] = (float)bci;
      rsd[w * 16 + b] = -1.0e300;
    }
  }
}

// ---------------------------------------------------------------------------
extern "C" void kernel_launch(void* const* d_in, const int* in_sizes, int n_in,
                              void* d_out, int out_size, void* d_ws, size_t ws_size,
                              hipStream_t stream) {
  const float* x = (const float*)d_in[0];
  const float* E = (const float*)d_in[1];
  float* out = (float*)d_out;

  if (ws_size < WS_NEED) {
    retr_fused<<<dim3(B_ROWS / RB), NTF, 0, stream>>>(x, E, out);
    return;
  }

  uint8_t* Xfp = (uint8_t*)d_ws;
  uint8_t* Efp = (uint8_t*)((char*)d_ws + EF_OFF);
  float*   csp = (float*)((char*)d_ws + CS_OFF);
  int*     cip = (int*)((char*)d_ws + CI_OFF);

  convert_frag8<<<dim3((B32N * KSTEPS * 64) / 256), 256, 0, stream>>>(x, Xfp, B32N);
  convert_frag8<<<dim3((E32N * KSTEPS * 64) / 256), 256, 0, stream>>>(E, Efp, E32N);
  gemm_topk<<<dim3(NBB * NGRP), 512, 0, stream>>>(Efp, Xfp, csp, cip);
  final_merge<<<dim3(B_ROWS), 64, 0, stream>>>(x, E, csp, cip, out);
}

// Round 18
// 821.457 us; speedup vs baseline: 2.0227x; 2.0227x over previous
//
#include <hip/hip_runtime.h>
#include <hip/hip_fp8.h>
#include <math.h>
#include <stdint.h>

#define B_ROWS 4096
#define D_DIM  768
#define M_ROWS 100000
#define K_TOP  10

// ---------------- MFMA-path constants ----------------
#define KSTEPS 48          // 768 / 16
#define E32N   3125        // evidence 32-row tiles
#define B32N   128         // batch 32-row tiles
#define NGRP   48          // evidence groups (grid = 16 bb x 48 g = 768 blocks)
#define NBB    16
#define NIT4   782         // ceil(3125/4): block-iterations of 128 evid rows
#define CAND   6           // candidates kept per (row, group)  (48*6 = 288/row)
#define KCN    12          // K-chunks of 64 per j
#define LTK    5           // per-lane top-k length (4 lists/column)
#define TILEB  24576       // bytes per 32-row fp8 fragment tile (48 ks * 512)

typedef long i64;
typedef float f32x16 __attribute__((ext_vector_type(16)));

// workspace layout (bytes)
#define XF_BYTES (128ull * TILEB)
#define EF_OFF   XF_BYTES
#define EF_BYTES (3125ull * TILEB)
#define CS_OFF   (EF_OFF + EF_BYTES)
#define CS_BYTES (4096ull * NGRP * CAND * 4)
#define CI_OFF   (CS_OFF + CS_BYTES)
#define CI_BYTES (4096ull * NGRP * CAND * 4)
#define WS_NEED  (CI_OFF + CI_BYTES)

// ---------------------------------------------------------------------------
// Convert fp32 [rows][768] -> fp8 e4m3 fragment-tiled
// [band32][ks48][lane64][j8] bytes.
// ---------------------------------------------------------------------------
__global__ __launch_bounds__(256) void convert_frag8(
    const float* __restrict__ src, uint8_t* __restrict__ dst, int nband)
{
  int tid  = blockIdx.x * 256 + threadIdx.x;
  int l    = tid & 63;
  int rest = tid >> 6;
  int ks   = rest % KSTEPS;
  int band = rest / KSTEPS;
  if (band >= nband) return;
  int row = band * 32 + (l & 31);
  int k0  = ks * 16 + 8 * (l >> 5);
  const float* s = src + (size_t)row * D_DIM + k0;
  float4 v0 = *(const float4*)s;
  float4 v1 = *(const float4*)(s + 4);
  unsigned long long o = 0;
  o |= (unsigned long long)(__hip_fp8_e4m3(v0.x).__x) << 0;
  o |= (unsigned long long)(__hip_fp8_e4m3(v0.y).__x) << 8;
  o |= (unsigned long long)(__hip_fp8_e4m3(v0.z).__x) << 16;
  o |= (unsigned long long)(__hip_fp8_e4m3(v0.w).__x) << 24;
  o |= (unsigned long long)(__hip_fp8_e4m3(v1.x).__x) << 32;
  o |= (unsigned long long)(__hip_fp8_e4m3(v1.y).__x) << 40;
  o |= (unsigned long long)(__hip_fp8_e4m3(v1.z).__x) << 48;
  o |= (unsigned long long)(__hip_fp8_e4m3(v1.w).__x) << 56;
  *(unsigned long long*)(dst + ((size_t)(band * KSTEPS + ks) << 9) + l * 8) = o;
}

// sorted top-5 insert (descending), static-indexed
__device__ __forceinline__ void ins5(float (&ts)[LTK], int (&ti)[LTK],
                                     float s, int idx)
{
  ts[LTK - 1] = s; ti[LTK - 1] = idx;
#pragma unroll
  for (int q = LTK - 1; q > 0; --q) {
    if (ts[q] > ts[q - 1]) {
      float a = ts[q]; ts[q] = ts[q - 1]; ts[q - 1] = a;
      int   b = ti[q]; ti[q] = ti[q - 1]; ti[q - 1] = b;
    }
  }
}

__device__ __forceinline__ float max16(const f32x16& v)
{
  float a = fmaxf(fmaxf(v[0], v[1]), fmaxf(v[2], v[3]));
  float b = fmaxf(fmaxf(v[4], v[5]), fmaxf(v[6], v[7]));
  float c = fmaxf(fmaxf(v[8], v[9]), fmaxf(v[10], v[11]));
  float d = fmaxf(fmaxf(v[12], v[13]), fmaxf(v[14], v[15]));
  return fmaxf(fmaxf(a, b), fmaxf(c, d));
}

__device__ __forceinline__ void gll16(const void* src, void* dst)
{
  __builtin_amdgcn_global_load_lds(
      (const __attribute__((address_space(1))) void*)(uintptr_t)src,
      (__attribute__((address_space(3))) void*)(uint32_t)(uintptr_t)dst,
      16, 0, 0);
}

// ---------------------------------------------------------------------------
// GEMM + fused per-lane top-k, fp8 e4m3.  r13's proven schedule, block shrunk
// to 8 waves / 48 KB LDS so TWO independent blocks co-reside per CU
// (2 x 48 KB = 96 <= 160 KB; 16 waves/CU = 4 waves/SIMD at <=128 regs):
// when one block sits in its vmcnt(0)+barrier drain, the other block's
// waves compute.  launch_bounds(512,4) — NOT 6: r17's (512,6) capped regs
// at 85 < the 104 needed (64 AGPR acc + ~40 VGPR) and spilled the
// accumulators to scratch (WRITE_SIZE 1.2 GB, 2.3x regression).
// Per block-iteration j: 128 evid x 256 batch, K=768.
// 8 waves = 2 evid-waves x 4 batch-waves, 2x2 tiles each.
// Buffer (24576 B): E tiles 0..3 at et*2048; X tiles 0..7 at 8192+xt*2048;
// frag kk at +kk*512.  Waves 0..3 stage E tile w (2 glls); waves 4..7 stage
// X tiles 2(w-4),2(w-4)+1 (4 glls).
// Merge scratch: ds = 20 KB at lds+0, di = 20 KB at lds+24576 (disjoint).
// ---------------------------------------------------------------------------
__global__ __launch_bounds__(512, 4) void gemm_topk(
    const uint8_t* __restrict__ Ef, const uint8_t* __restrict__ Xf,
    float* __restrict__ cs, int* __restrict__ ci)
{
  __shared__ char lds[2][24576];   // 2 x 24 KB (double buffer)

  const int t    = threadIdx.x;
  const int lane = t & 63;
  const int w    = t >> 6;      // 0..7
  const int ew   = w >> 2;      // 0..1  evid-wave (2 e-tiles each)
  const int bw   = w & 3;       // 0..3  batch-wave (2 x-tiles each)

  // XCD-aware remap: id%8 = XCD; each XCD hosts 6 g-values x all 16 bb.
  const int id  = blockIdx.x;           // 0..767
  const int xcd = id & 7;
  const int q8  = id >> 3;              // 0..95
  const int bb  = q8 & 15;              // batch block 0..15
  const int g   = xcd * 6 + (q8 >> 4);  // evidence group 0..47
  const int niter = 16 + (g < (NIT4 - NGRP * 16) ? 1 : 0);   // 782 = 48*16+14

  const bool isE = (w < 4);
  const uint32_t dE  = (uint32_t)w * 2048 + lane * 16;            // E tile w
  const uint32_t dX0 = 8192u + (uint32_t)(2 * (w - 4)) * 2048 + lane * 16;
  const uint32_t dX1 = dX0 + 2048;

  // X staging sources (j-invariant)
  const uint8_t* xb0 = Xf + (size_t)(bb * 8 + 2 * (w - 4)) * TILEB + lane * 16;
  const uint8_t* xb1 = xb0 + TILEB;

  auto STAGE = [&](const uint8_t* s0, const uint8_t* s1, char* base) {
    if (isE) {
      gll16(s0,        base + dE);
      gll16(s0 + 1024, base + dE + 1024);
    } else {
      gll16(s0,        base + dX0);
      gll16(s0 + 1024, base + dX0 + 1024);
      gll16(s1,        base + dX1);
      gll16(s1 + 1024, base + dX1 + 1024);
    }
  };

  float ts0[LTK], ts1[LTK]; int ti0[LTK], ti1[LTK];
#pragma unroll
  for (int q = 0; q < LTK; ++q) {
    ts0[q] = -INFINITY; ts1[q] = -INFINITY;
    ti0[q] = 0x7fffffff; ti1[q] = 0x7fffffff;
  }

  char* buf0 = &lds[0][0];
  char* buf1 = &lds[1][0];
  const char* rb0p = buf0 + lane * 8;
  const char* rb1p = buf1 + lane * 8;

#pragma unroll 1
  for (int j = 0; j < niter; ++j) {
    const int it = g + NGRP * j;          // global 128-row block-iteration

    const uint8_t* sE = xb0;              // placeholder for X waves
    if (isE) {
      int e32 = it * 4 + w; if (e32 > E32N - 1) e32 = E32N - 1;
      sE = Ef + (size_t)e32 * TILEB + lane * 16;
    }

    f32x16 acc0[2], acc1[2];
#pragma unroll
    for (int e = 0; e < 2; ++e) {
#pragma unroll
      for (int q = 0; q < 16; ++q) { acc0[e][q] = 0.f; acc1[e][q] = 0.f; }
    }

    // stage chunk 0 into buf0 (freed by previous j's final barrier)
    const uint8_t* sc0 = isE ? sE : xb0;
    const uint8_t* sc1 = xb1;
    STAGE(sc0, sc1, buf0);
    sc0 += 2048; sc1 += 2048;

#pragma unroll 1
    for (int kc = 0; kc < KCN; ++kc) {
      asm volatile("s_waitcnt vmcnt(0)" ::: "memory"); // chunk-kc loads landed
      __builtin_amdgcn_s_barrier();                    // this block staged kc

      const char* rp = (kc & 1) ? rb1p : rb0p;
      char* dp = (kc & 1) ? buf0 : buf1;

      if (kc < KCN - 1) {                              // stage chunk kc+1 early
        STAGE(sc0, sc1, dp);
        sc0 += 2048; sc1 += 2048;
      }

#pragma unroll
      for (int kk = 0; kk < 4; ++kk) {
        i64 a[2], b[2];
#pragma unroll
        for (int e = 0; e < 2; ++e)
          a[e] = *(const i64*)(rp + ((ew * 2 + e) * 2048 + kk * 512));
#pragma unroll
        for (int x2 = 0; x2 < 2; ++x2)
          b[x2] = *(const i64*)(rp + (8192 + (bw * 2 + x2) * 2048 + kk * 512));
#pragma unroll
        for (int e = 0; e < 2; ++e) {
          acc0[e] = __builtin_amdgcn_mfma_f32_32x32x16_fp8_fp8(a[e], b[0], acc0[e], 0, 0, 0);
          acc1[e] = __builtin_amdgcn_mfma_f32_32x32x16_fp8_fp8(a[e], b[1], acc1[e], 0, 0, 0);
        }
      }
    }

    // inserts, max-prefiltered per 16-value tile
    // C/D map: col=lane&31, row=(q&3)+8*(q>>2)+4*(lane>>5)
#pragma unroll
    for (int e = 0; e < 2; ++e) {
      const int ebase = (it * 4 + ew * 2 + e) * 32 + 4 * (lane >> 5);
      if (max16(acc0[e]) > ts0[LTK - 1]) {
#pragma unroll
        for (int q = 0; q < 16; ++q) {
          int eidx = ebase + (q & 3) + 8 * (q >> 2);
          float s = acc0[e][q];
          if (eidx < M_ROWS && s > ts0[LTK - 1]) ins5(ts0, ti0, s, eidx);
        }
      }
      if (max16(acc1[e]) > ts1[LTK - 1]) {
#pragma unroll
        for (int q = 0; q < 16; ++q) {
          int eidx = ebase + (q & 3) + 8 * (q >> 2);
          float s = acc1[e][q];
          if (eidx < M_ROWS && s > ts1[LTK - 1]) ins5(ts1, ti1, s, eidx);
        }
      }
    }
  }

  // ---- merge per batch-col: 4 lists (2 evid-waves x 2 lane-halves) -> top-6
  // ds = 5120 floats (20 KB) at lds+0; di = 5120 ints (20 KB) at lds+24576.
  __syncthreads();
  float* ds = (float*)&lds[0][0];
  int*   di = (int*)(&lds[0][0] + 24576);
  {
    int half = lane >> 5, cl = lane & 31;
    int base0 = ((((ew * 2 + half) * 4 + bw) * 2 + 0) * 32 + cl) * LTK;
    int base1 = ((((ew * 2 + half) * 4 + bw) * 2 + 1) * 32 + cl) * LTK;
#pragma unroll
    for (int q = 0; q < LTK; ++q) {
      ds[base0 + q] = ts0[q]; di[base0 + q] = ti0[q];
      ds[base1 + q] = ts1[q]; di[base1 + q] = ti1[q];
    }
  }
  __syncthreads();
  if (t < 256) {
    int c = t; int bw2 = c >> 6, bt2 = (c >> 5) & 1, cl2 = c & 31;
    int hb[4];
#pragma unroll
    for (int u = 0; u < 4; ++u) {
      int ew2 = u >> 1, h2 = u & 1;
      hb[u] = ((((ew2 * 2 + h2) * 4 + bw2) * 2 + bt2) * 32 + cl2) * LTK;
    }
    const int row = bb * 256 + c;
    float* ocs = cs + ((size_t)row * NGRP + g) * CAND;
    int*   oci = ci + ((size_t)row * NGRP + g) * CAND;
    for (int o = 0; o < CAND; ++o) {
      float best = -INFINITY; int bidx = 0x7fffffff; int bu = 0, bq = 0;
#pragma unroll
      for (int u = 0; u < 4; ++u) {
        for (int q = 0; q < LTK; ++q) {
          float s = ds[hb[u] + q]; int id2 = di[hb[u] + q];
          if (s > best || (s == best && id2 < bidx)) { best = s; bidx = id2; bu = u; bq = q; }
        }
      }
      ds[hb[bu] + bq] = -INFINITY;
      ocs[o] = best; oci[o] = bidx;
    }
  }
}

// ---------------------------------------------------------------------------
// Final: per row merge 48*6=288 candidates -> approx top-32 (fp8 noise
// margin — the r13/r15-proven width) -> fp64 rescore -> exact top-10.
// ---------------------------------------------------------------------------
#define NCAND (NGRP * CAND)   // 288

__global__ __launch_bounds__(64) void final_merge(
    const float* __restrict__ x, const float* __restrict__ E,
    const float* __restrict__ cs, const int* __restrict__ ci,
    float* __restrict__ out)
{
  __shared__ float ls[NCAND]; __shared__ int li[NCAND];
  __shared__ int c32[32]; __shared__ double rs[32];
  const int row = blockIdx.x;
  const int lane = threadIdx.x;
  for (int q = lane; q < NCAND; q += 64) {
    ls[q] = cs[(size_t)row * NCAND + q];
    li[q] = ci[(size_t)row * NCAND + q];
  }
  __syncthreads();

  for (int o = 0; o < 32; ++o) {
    float bs = -INFINITY; int bi = 0x7fffffff; int bp = 0;
    for (int q = lane; q < NCAND; q += 64) {
      float s = ls[q];
      if (s > bs || (s == bs && li[q] < bi)) { bs = s; bi = li[q]; bp = q; }
    }
#pragma unroll
    for (int mk = 1; mk <= 32; mk <<= 1) {
      float qs = __shfl_xor(bs, mk, 64);
      int   qi = __shfl_xor(bi, mk, 64);
      int   qp = __shfl_xor(bp, mk, 64);
      if (qs > bs || (qs == bs && qi < bi)) { bs = qs; bi = qi; bp = qp; }
    }
    if (lane == 0) { c32[o] = bi; ls[bp] = -INFINITY; }
    __syncthreads();
  }

  {
    int cd = lane >> 1, p = lane & 1;      // 2 lanes per candidate, 384 elems
    int cid = c32[cd];
    if ((unsigned)cid >= M_ROWS) cid = 0;  // defensive: wrong, not a fault
    const float* Er = E + (size_t)cid * D_DIM + p * 384;
    const float* Xr = x + (size_t)row * D_DIM + p * 384;
    double s = 0.0;
#pragma unroll 8
    for (int d = 0; d < 384; ++d) s += (double)Xr[d] * (double)Er[d];
    s += __shfl_xor(s, 1, 64);
    if (p == 0) rs[cd] = s;
  }
  __syncthreads();

  if (lane == 0) {
    for (int o = 0; o < K_TOP; ++o) {
      double bs = rs[0]; int bc = c32[0]; int b = 0;
      for (int q = 1; q < 32; ++q) {
        double v = rs[q]; int cq = c32[q];
        if (v > bs || (v == bs && cq < bc)) { bs = v; bc = cq; b = q; }
      }
      out[(size_t)row * K_TOP + o] = (float)bs;
      out[(size_t)B_ROWS * K_TOP + (size_t)row * K_TOP + o] = (float)bc;
      rs[b] = -1.0e300;
    }
  }
}

// ---------------------------------------------------------------------------
// Fallback (round-2 kernel) if ws_size is insufficient.
// ---------------------------------------------------------------------------
#define RB   16
#define GQ   64
#define MMF  4
#define NJ   391
#define NTF  1024
#define XPAD 772
#define DQ4  192

__global__ __launch_bounds__(NTF, 4) void retr_fused(
    const float* __restrict__ x, const float* __restrict__ E,
    float* __restrict__ out)
{
  __shared__ float smem[21248];
  const int t = threadIdx.x;
  const int r = t & 15;
  const int g = t >> 4;
  const int rb0 = blockIdx.x * RB;
  {
    const float4* xg = (const float4*)(x + (size_t)rb0 * D_DIM);
    for (int q = t; q < RB * DQ4; q += NTF) {
      int row = q / DQ4, c4 = q % DQ4;
      float4 v = xg[q];
      *(float4*)(smem + row * XPAD + c4 * 4) = v;
    }
  }
  __syncthreads();
  float ts[K_TOP]; int ti[K_TOP];
#pragma unroll
  for (int q = 0; q < K_TOP; ++q) { ts[q] = -INFINITY; ti[q] = 0x7fffffff; }
  const float4* xr4 = (const float4*)(smem + r * XPAD);
  for (int j = 0; j < NJ; ++j) {
    const int m0 = (g + (j << 6)) * MMF;
    const float4* ep[MMF];
#pragma unroll
    for (int mm = 0; mm < MMF; ++mm) {
      int ml = m0 + mm;
      int mc = (ml < M_ROWS) ? ml : (M_ROWS - 1);
      ep[mm] = (const float4*)(E + (size_t)mc * D_DIM);
    }
    float4 acc[MMF];
#pragma unroll
    for (int mm = 0; mm < MMF; ++mm) acc[mm] = make_float4(0.f, 0.f, 0.f, 0.f);
#pragma unroll 4
    for (int dq = 0; dq < DQ4; ++dq) {
      float4 xv = xr4[dq];
#pragma unroll
      for (int mm = 0; mm < MMF; ++mm) {
        float4 e = ep[mm][dq];
        acc[mm].x += e.x * xv.x; acc[mm].y += e.y * xv.y;
        acc[mm].z += e.z * xv.z; acc[mm].w += e.w * xv.w;
      }
    }
#pragma unroll
    for (int mm = 0; mm < MMF; ++mm) {
      int ml = m0 + mm;
      float s = (acc[mm].x + acc[mm].y) + (acc[mm].z + acc[mm].w);
      if (ml < M_ROWS && s > ts[K_TOP - 1]) {
        ts[K_TOP - 1] = s; ti[K_TOP - 1] = ml;
#pragma unroll
        for (int q = K_TOP - 1; q > 0; --q) {
          if (ts[q] > ts[q - 1]) {
            float tf = ts[q]; ts[q] = ts[q - 1]; ts[q - 1] = tf;
            int   tq = ti[q]; ti[q] = ti[q - 1]; ti[q - 1] = tq;
          }
        }
      }
    }
  }
  __syncthreads();
  float*  cs  = smem;
  int*    ci  = (int*)(smem + 10240);
  int*    cnd = (int*)(smem + 20480);
  double* rsd = (double*)(smem + 20736);
#pragma unroll
  for (int q = 0; q < K_TOP; ++q) {
    cs[(r * GQ + g) * K_TOP + q] = ts[q];
    ci[(r * GQ + g) * K_TOP + q] = ti[q];
  }
  __syncthreads();
  const int w = t >> 6;
  const int lane = t & 63;
  {
    float ms[K_TOP]; int mi[K_TOP];
#pragma unroll
    for (int q = 0; q < K_TOP; ++q) {
      ms[q] = cs[(w * GQ + lane) * K_TOP + q];
      mi[q] = ci[(w * GQ + lane) * K_TOP + q];
    }
    for (int o = 0; o < 16; ++o) {
      float hs = ms[0]; int hi = mi[0];
      float bs = hs;    int bi = hi;
#pragma unroll
      for (int mk = 1; mk <= 32; mk <<= 1) {
        float qs = __shfl_xor(bs, mk, 64);
        int   qi = __shfl_xor(bi, mk, 64);
        if (qs > bs || (qs == bs && qi < bi)) { bs = qs; bi = qi; }
      }
      bool win = (hs == bs) && (hi == bi);
      if (win) {
#pragma unroll
        for (int q = 0; q < K_TOP - 1; ++q) { ms[q] = ms[q + 1]; mi[q] = mi[q + 1]; }
        ms[K_TOP - 1] = -INFINITY; mi[K_TOP - 1] = 0x7fffffff;
      }
      if (lane == 0) cnd[w * 16 + o] = bi;
    }
  }
  __syncthreads();
  {
    int cand = lane >> 2, p = lane & 3;
    int cid = cnd[w * 16 + cand];
    const float* Er = E + (size_t)cid * D_DIM + p * 192;
    const float* Xr = x + (size_t)(rb0 + w) * D_DIM + p * 192;
    double s = 0.0;
#pragma unroll 8
    for (int d = 0; d < 192; ++d) s += (double)Xr[d] * (double)Er[d];
    s += __shfl_xor(s, 1, 64);
    s += __shfl_xor(s, 2, 64);
    if (p == 0) rsd[w * 16 + cand] = s;
  }
  __syncthreads();
  if (lane == 0) {
    const int row = rb0 + w;
    for (int o = 0; o < K_TOP; ++o) {
      double bsv = rsd[w * 16 + 0]; int bci = cnd[w * 16 + 0]; int b = 0;
      for (int q = 1; q < 16; ++q) {
        double v = rsd[w * 16 + q]; int c = cnd[w * 16 + q];
        if (v > bsv || (v == bsv && c < bci)) { bsv = v; bci = c; b = q; }
      }
      out[(size_t)row * K_TOP + o] = (float)bsv;
      out[(size_t)B_ROWS * K_TOP + (size_t)row * K_TOP + o] = (float)bci;
      rsd[w * 16 + b] = -1.0e300;
    }
  }
}

// ---------------------------------------------------------------------------
extern "C" void kernel_launch(void* const* d_in, const int* in_sizes, int n_in,
                              void* d_out, int out_size, void* d_ws, size_t ws_size,
                              hipStream_t stream) {
  const float* x = (const float*)d_in[0];
  const float* E = (const float*)d_in[1];
  float* out = (float*)d_out;

  if (ws_size < WS_NEED) {
    retr_fused<<<dim3(B_ROWS / RB), NTF, 0, stream>>>(x, E, out);
    return;
  }

  uint8_t* Xfp = (uint8_t*)d_ws;
  uint8_t* Efp = (uint8_t*)((char*)d_ws + EF_OFF);
  float*   csp = (float*)((char*)d_ws + CS_OFF);
  int*     cip = (int*)((char*)d_ws + CI_OFF);

  convert_frag8<<<dim3((B32N * KSTEPS * 64) / 256), 256, 0, stream>>>(x, Xfp, B32N);
  convert_frag8<<<dim3((E32N * KSTEPS * 64) / 256), 256, 0, stream>>>(E, Efp, E32N);
  gemm_topk<<<dim3(NBB * NGRP), 512, 0, stream>>>(Efp, Xfp, csp, cip);
  final_merge<<<dim3(B_ROWS), 64, 0, stream>>>(x, E, csp, cip, out);
}